// Round 7
// baseline (271.369 us; speedup 1.0000x reference)
//
#include <hip/hip_runtime.h>
#include <math.h>

#define L_  1024
#define S_  2048
#define NB  4
#define E_  512
#define H_  8
#define HD_ 64
#define SPLIT 2

constexpr float SCALING = 0.125f;   // (E/H)^-0.5 = 1/8
constexpr float LNEPS   = 1e-5f;

typedef __attribute__((ext_vector_type(8))) short s16x8;          // 8 bf16 MFMA frag
typedef __attribute__((ext_vector_type(8))) unsigned short u16x8; // 8 bf16 store
typedef __attribute__((ext_vector_type(4))) float f32x4;          // MFMA accumulator
typedef unsigned short ushort_t;

__device__ __forceinline__ unsigned short f2bf(float f) {
    unsigned u = __builtin_bit_cast(unsigned, f);
    u += 0x7fffu + ((u >> 16) & 1u);   // RNE
    return (unsigned short)(u >> 16);
}
__device__ __forceinline__ float bf2f(unsigned short h) {
    unsigned u = ((unsigned)h) << 16;
    return __builtin_bit_cast(float, u);
}
__device__ __forceinline__ unsigned packbf(float a, float b) {
    return (unsigned)f2bf(a) | ((unsigned)f2bf(b) << 16);
}

// ---------------------------------------------------------------------------
// Kernel 0: cast 4 fp32 arrays -> bf16 (query, value, ipw, opw)
// ---------------------------------------------------------------------------
__global__ __launch_bounds__(256)
void cast4_kernel(const float* __restrict__ s0, const float* __restrict__ s1,
                  const float* __restrict__ s2, const float* __restrict__ s3,
                  ushort_t* __restrict__ d0, ushort_t* __restrict__ d1,
                  ushort_t* __restrict__ d2, ushort_t* __restrict__ d3,
                  int c0, int c1, int c2, int c3)
{
    int i = blockIdx.x * 256 + threadIdx.x;
    const float* s; ushort_t* d; int off;
    if      (i < c0) { s = s0; d = d0; off = i; }
    else if (i < c1) { s = s1; d = d1; off = i - c0; }
    else if (i < c2) { s = s2; d = d2; off = i - c1; }
    else if (i < c3) { s = s3; d = d3; off = i - c2; }
    else return;
    const float4* sp = (const float4*)(s + (size_t)off * 8);
    float4 a = sp[0], b = sp[1];
    u16x8 o;
    o[0] = f2bf(a.x); o[1] = f2bf(a.y); o[2] = f2bf(a.z); o[3] = f2bf(a.w);
    o[4] = f2bf(b.x); o[5] = f2bf(b.y); o[6] = f2bf(b.z); o[7] = f2bf(b.w);
    *(u16x8*)(d + (size_t)off * 8) = o;
}

// ---------------------------------------------------------------------------
// Fused q+kv projection GEMM with rotary/bias/head-permute epilogue.
// Grid: 1280 blocks. bid<256: q path (fb 0..3, tb 0..63).
//       bid>=256: kv path (fb 0..7, tb 0..127); fb<4 -> K(+rotary), fb>=4 -> V.
// Tile 64 tokens x 128 feats, BK=32, 256 thr = 4 waves (2 row x 2 col).
// Rotary pair (2i,2i+1) = adjacent lanes -> one __shfl_xor(v,1).
// ---------------------------------------------------------------------------
__global__ __launch_bounds__(256)
void qkv_gemm_rope_kernel(const ushort_t* __restrict__ qbf,  // (4096,512) bf16
                          const ushort_t* __restrict__ vbf,  // (8192,512) bf16
                          const ushort_t* __restrict__ wbf,  // (1536,512) bf16
                          const float* __restrict__ ipb,     // (1536)
                          const float* __restrict__ qpos,    // (NB,L,512,2)
                          const float* __restrict__ vpos,    // (NB,S,512,2)
                          ushort_t* __restrict__ qrot,       // (NB,H,L,64)
                          ushort_t* __restrict__ krot,       // (NB,H,S,64)
                          ushort_t* __restrict__ vperm)      // (NB,H,S,64)
{
    __shared__ ushort_t As[64 * 32];
    __shared__ ushort_t Bs[128 * 32];
    const int t = threadIdx.x;
    const int w = t >> 6, l = t & 63;
    const int wr = w >> 1, wc = w & 1;
    const int g = l >> 4, c16 = l & 15;

    const int bid = blockIdx.x;
    const bool isq = bid < 256;
    int fb, tb;
    const ushort_t* Abase;
    const ushort_t* Wbase;
    if (isq) { fb = bid & 3;  tb = bid >> 2; Abase = qbf; Wbase = wbf; }
    else     { int b = bid - 256; fb = b & 7; tb = b >> 3; Abase = vbf; Wbase = wbf + 512 * 512; }
    const int m0 = tb * 64;
    const int n0 = fb * 128;
    const int Ltok = isq ? L_ : S_;

    f32x4 acc[2][4];
    #pragma unroll
    for (int m = 0; m < 2; ++m)
        #pragma unroll
        for (int n = 0; n < 4; ++n) acc[m][n] = (f32x4){0.f, 0.f, 0.f, 0.f};

    for (int k0 = 0; k0 < 512; k0 += 32) {
        // stage A (64 rows x 32 k) and B (128 rows x 32 k), chunk-XOR swizzled
        {
            int ch = t;                 // 256 chunks exactly
            int r = ch >> 2, c = ch & 3;
            s16x8 v = *(const s16x8*)(Abase + (size_t)(m0 + r) * 512 + k0 + c * 8);
            int cp = c ^ ((r >> 1) & 3);
            *(s16x8*)((char*)As + r * 64 + cp * 16) = v;
        }
        #pragma unroll
        for (int ch = t; ch < 512; ch += 256) {
            int r = ch >> 2, c = ch & 3;
            s16x8 v = *(const s16x8*)(Wbase + (size_t)(n0 + r) * 512 + k0 + c * 8);
            int cp = c ^ ((r >> 1) & 3);
            *(s16x8*)((char*)Bs + r * 64 + cp * 16) = v;
        }
        __syncthreads();
        s16x8 fa[2], fb4[4];
        #pragma unroll
        for (int m = 0; m < 2; ++m) {
            int r = wr * 32 + m * 16 + c16;
            fa[m] = *(const s16x8*)((char*)As + r * 64 + ((g ^ ((r >> 1) & 3)) * 16));
        }
        #pragma unroll
        for (int n = 0; n < 4; ++n) {
            int r = wc * 64 + n * 16 + c16;
            fb4[n] = *(const s16x8*)((char*)Bs + r * 64 + ((g ^ ((r >> 1) & 3)) * 16));
        }
        #pragma unroll
        for (int m = 0; m < 2; ++m)
            #pragma unroll
            for (int n = 0; n < 4; ++n)
                acc[m][n] = __builtin_amdgcn_mfma_f32_16x16x32_bf16(fa[m], fb4[n], acc[m][n], 0, 0, 0);
        __syncthreads();
    }

    // ---- fused epilogue: bias (+scale) (+rotary) -> bf16 head-permuted ----
    const bool dorot = isq || (n0 < 512);          // q and K paths
    const float sgn = (l & 1) ? 1.f : -1.f;
    const float* pos = isq ? qpos : vpos;
    #pragma unroll
    for (int m = 0; m < 2; ++m) {
        #pragma unroll
        for (int nf = 0; nf < 4; ++nf) {
            const int col = n0 + wc * 64 + nf * 16 + c16;     // 0..511 (q) / 0..1023 (kv)
            const float bia = ipb[isq ? col : 512 + col];
            #pragma unroll
            for (int r = 0; r < 4; ++r) {
                const int row = m0 + wr * 32 + m * 16 + g * 4 + r;
                const int tok = row >> 2, n = row & 3;
                float v = acc[m][nf][r] + bia;
                if (isq) v *= SCALING;
                if (dorot) {
                    float2 cs = *(const float2*)(pos + (((size_t)n * Ltok + tok) * 512 + col) * 2);
                    float p = __shfl_xor(v, 1, 64);
                    float o = v * cs.x + sgn * p * cs.y;
                    const int hh = col >> 6, hd = col & 63;
                    ushort_t* dst = isq
                        ? qrot + ((size_t)(n * H_ + hh) * L_ + tok) * HD_ + hd
                        : krot + ((size_t)(n * H_ + hh) * S_ + tok) * HD_ + hd;
                    *dst = f2bf(o);
                } else {
                    const int e = col - 512;
                    const int hh = e >> 6, hd = e & 63;
                    vperm[((size_t)(n * H_ + hh) * S_ + tok) * HD_ + hd] = f2bf(v);
                }
            }
        }
    }
}

// ---------------------------------------------------------------------------
// bf16 MFMA GEMM with fused bias+residual epilogue (out projection)
// ---------------------------------------------------------------------------
template<int MR, int EPI>
__global__ __launch_bounds__(256)
void gemm_bf16_kernel(const ushort_t* __restrict__ A,
                      const ushort_t* __restrict__ Bw,
                      ushort_t* __restrict__ Cb,
                      const float* __restrict__ bias,
                      const float* __restrict__ resid,
                      float* __restrict__ Y,
                      int nfeat)
{
    constexpr int BM = MR * 32;
    __shared__ ushort_t As[BM * 32];
    __shared__ ushort_t Bs[128 * 32];
    const int t = threadIdx.x;
    const int w = t >> 6, l = t & 63;
    const int wr = w >> 1, wc = w & 1;
    const int g = l >> 4, c16 = l & 15;
    const int m0 = blockIdx.y * BM;
    const int n0 = blockIdx.x * 128;

    f32x4 acc[MR][4];
    #pragma unroll
    for (int m = 0; m < MR; ++m)
        #pragma unroll
        for (int n = 0; n < 4; ++n) acc[m][n] = (f32x4){0.f, 0.f, 0.f, 0.f};

    for (int k0 = 0; k0 < 512; k0 += 32) {
        #pragma unroll
        for (int ch = t; ch < BM * 4; ch += 256) {
            int r = ch >> 2, c = ch & 3;
            s16x8 v = *(const s16x8*)(A + (size_t)(m0 + r) * 512 + k0 + c * 8);
            int cp = c ^ ((r >> 1) & 3);
            *(s16x8*)((char*)As + r * 64 + cp * 16) = v;
        }
        #pragma unroll
        for (int ch = t; ch < 512; ch += 256) {
            int r = ch >> 2, c = ch & 3;
            s16x8 v = *(const s16x8*)(Bw + (size_t)(n0 + r) * 512 + k0 + c * 8);
            int cp = c ^ ((r >> 1) & 3);
            *(s16x8*)((char*)Bs + r * 64 + cp * 16) = v;
        }
        __syncthreads();
        s16x8 fa[MR], fb[4];
        #pragma unroll
        for (int m = 0; m < MR; ++m) {
            int r = wr * (MR * 16) + m * 16 + c16;
            fa[m] = *(const s16x8*)((char*)As + r * 64 + ((g ^ ((r >> 1) & 3)) * 16));
        }
        #pragma unroll
        for (int n = 0; n < 4; ++n) {
            int r = wc * 64 + n * 16 + c16;
            fb[n] = *(const s16x8*)((char*)Bs + r * 64 + ((g ^ ((r >> 1) & 3)) * 16));
        }
        #pragma unroll
        for (int m = 0; m < MR; ++m)
            #pragma unroll
            for (int n = 0; n < 4; ++n)
                acc[m][n] = __builtin_amdgcn_mfma_f32_16x16x32_bf16(fa[m], fb[n], acc[m][n], 0, 0, 0);
        __syncthreads();
    }

    #pragma unroll
    for (int m = 0; m < MR; ++m) {
        #pragma unroll
        for (int n = 0; n < 4; ++n) {
            int col = n0 + wc * 64 + n * 16 + c16;
            #pragma unroll
            for (int r = 0; r < 4; ++r) {
                int row = m0 + wr * (MR * 16) + m * 16 + g * 4 + r;
                if (EPI == 0) {
                    Cb[(size_t)row * nfeat + col] = f2bf(acc[m][n][r]);
                } else {
                    float v = acc[m][n][r] + bias[col] + resid[(size_t)row * 512 + col];
                    Y[(size_t)row * 512 + col] = v;
                }
            }
        }
    }
}

// ---------------------------------------------------------------------------
// V transpose (NB,H,S,64) -> (NB,H,64,S)
// ---------------------------------------------------------------------------
__global__ __launch_bounds__(256)
void vtrans_kernel(const ushort_t* __restrict__ vin,
                   ushort_t* __restrict__ vout)
{
    __shared__ ushort_t T[64][68];
    const int t  = threadIdx.x;
    const int s0 = blockIdx.x * 64;
    const int h  = blockIdx.y, n = blockIdx.z;
    const ushort_t* src = vin + (size_t)((n * H_ + h) * S_ + s0) * HD_;
    #pragma unroll
    for (int p = 0; p < 4; ++p) {
        int e = p * 1024 + t * 4;
        int row = e >> 6, col = e & 63;
        *(ushort4*)&T[row][col] = *(const ushort4*)(src + row * HD_ + col);
    }
    __syncthreads();
    ushort_t* dst = vout + (size_t)(n * H_ + h) * HD_ * S_ + s0;
    #pragma unroll
    for (int p = 0; p < 4; ++p) {
        int d  = p * 16 + (t >> 4);
        int sc = (t & 15) * 4;
        ushort4 o;
        o.x = T[sc + 0][d]; o.y = T[sc + 1][d]; o.z = T[sc + 2][d]; o.w = T[sc + 3][d];
        *(ushort4*)(dst + (size_t)d * S_ + sc) = o;
    }
}

// ---------------------------------------------------------------------------
// MFMA flash attention, swapped-operand QK^T + S-split partials (as R6)
// ---------------------------------------------------------------------------
__global__ __launch_bounds__(256)
void attn_mfma_kernel(const ushort_t* __restrict__ qg,
                      const ushort_t* __restrict__ kg,
                      const ushort_t* __restrict__ vtg,
                      float* __restrict__ pctx,
                      float2* __restrict__ pml)
{
    __shared__ __align__(16) char smem[40960];
    char* Kb0 = smem;
    char* Kb1 = smem + 8192;
    char* Vb0 = smem + 16384;
    char* Vb1 = smem + 24576;
    const int t = threadIdx.x;
    const int w = t >> 6, l = t & 63;
    char* Ps = smem + 32768 + w * 2048;
    const int g = l >> 4, c16 = l & 15;
    const int h = blockIdx.y;
    const int n = blockIdx.z / SPLIT, sp = blockIdx.z % SPLIT;
    const int qb0 = blockIdx.x * 64;
    constexpr int NT = (S_ / SPLIT) / 64;

    const char* kbase  = (const char*)(kg  + (size_t)(n * H_ + h) * S_ * HD_)
                       + (size_t)sp * (S_ / SPLIT) * 128;
    const char* vtbase = (const char*)(vtg + (size_t)(n * H_ + h) * HD_ * S_)
                       + (size_t)sp * (S_ / SPLIT) * 2;

    const int qgl = qb0 + w * 16 + c16;
    const char* qrow = (const char*)(qg + (size_t)((n * H_ + h) * L_ + qgl) * HD_);
    s16x8 qf0 = *(const s16x8*)(qrow + 16 * g);
    s16x8 qf1 = *(const s16x8*)(qrow + 64 + 16 * g);

    const int srow = t >> 3;
    const int scol = (t & 7) * 16;

    float mrun = -1e30f, lrun = 0.f;
    f32x4 oacc[4];
    #pragma unroll
    for (int s2 = 0; s2 < 4; ++s2) oacc[s2] = (f32x4){0.f, 0.f, 0.f, 0.f};

    uint4 kreg[2], vreg[2];
    #pragma unroll
    for (int c = 0; c < 2; ++c) {
        int row = c * 32 + srow;
        kreg[c] = *(const uint4*)(kbase  + (size_t)row * 128 + scol);
        vreg[c] = *(const uint4*)(vtbase + (size_t)row * (S_ * 2) + scol);
    }
    #pragma unroll
    for (int c = 0; c < 2; ++c) {
        int row = c * 32 + srow;
        int sw  = scol ^ ((row & 7) << 4);
        *(uint4*)(Kb0 + row * 128 + sw) = kreg[c];
        *(uint4*)(Vb0 + row * 128 + sw) = vreg[c];
    }
    __syncthreads();

    int cur = 0;
    for (int st = 0; st < NT; ++st) {
        if (st + 1 < NT) {
            const char* kP = kbase  + (size_t)(st + 1) * 64 * 128;
            const char* vP = vtbase + (size_t)(st + 1) * 128;
            #pragma unroll
            for (int c = 0; c < 2; ++c) {
                int row = c * 32 + srow;
                kreg[c] = *(const uint4*)(kP + (size_t)row * 128 + scol);
                vreg[c] = *(const uint4*)(vP + (size_t)row * (S_ * 2) + scol);
            }
        }
        char* K = cur ? Kb1 : Kb0;
        char* V = cur ? Vb1 : Vb0;

        f32x4 sacc[4];
        #pragma unroll
        for (int sub = 0; sub < 4; ++sub) {
            int row = sub * 16 + c16;
            int x = (row & 7) << 4;
            s16x8 kf0 = *(const s16x8*)(K + row * 128 + ((16 * g) ^ x));
            s16x8 kf1 = *(const s16x8*)(K + row * 128 + ((64 + 16 * g) ^ x));
            f32x4 z = (f32x4){0.f, 0.f, 0.f, 0.f};
            z = __builtin_amdgcn_mfma_f32_16x16x32_bf16(kf0, qf0, z, 0, 0, 0);
            z = __builtin_amdgcn_mfma_f32_16x16x32_bf16(kf1, qf1, z, 0, 0, 0);
            sacc[sub] = z;
        }

        float mloc = sacc[0][0];
        #pragma unroll
        for (int sub = 0; sub < 4; ++sub)
            #pragma unroll
            for (int r = 0; r < 4; ++r) mloc = fmaxf(mloc, sacc[sub][r]);
        mloc = fmaxf(mloc, __shfl_xor(mloc, 16, 64));
        mloc = fmaxf(mloc, __shfl_xor(mloc, 32, 64));
        float mnew = fmaxf(mrun, mloc);
        float scl = __expf(mrun - mnew);
        mrun = mnew;

        float p[4][4];
        float ps = 0.f;
        #pragma unroll
        for (int sub = 0; sub < 4; ++sub)
            #pragma unroll
            for (int r = 0; r < 4; ++r) {
                float e = __expf(sacc[sub][r] - mnew);
                p[sub][r] = e;
                ps += e;
            }
        ps += __shfl_xor(ps, 16, 64);
        ps += __shfl_xor(ps, 32, 64);
        lrun = lrun * scl + ps;

        #pragma unroll
        for (int sub = 0; sub < 4; ++sub) {
            uint2 pk;
            pk.x = packbf(p[sub][0], p[sub][1]);
            pk.y = packbf(p[sub][2], p[sub][3]);
            int by = (32 * sub + 8 * g) ^ ((c16 & 7) << 4);
            *(uint2*)(Ps + c16 * 128 + by) = pk;
        }

        float sclr[4];
        #pragma unroll
        for (int r = 0; r < 4; ++r) sclr[r] = __shfl(scl, 4 * g + r, 16);
        #pragma unroll
        for (int s2 = 0; s2 < 4; ++s2)
            #pragma unroll
            for (int r = 0; r < 4; ++r) oacc[s2][r] *= sclr[r];

        #pragma unroll
        for (int sh = 0; sh < 2; ++sh) {
            s16x8 pf = *(const s16x8*)(Ps + c16 * 128 + ((64 * sh + 16 * g) ^ ((c16 & 7) << 4)));
            #pragma unroll
            for (int s2 = 0; s2 < 4; ++s2) {
                int row = s2 * 16 + c16;
                int x = (row & 7) << 4;
                s16x8 vf = *(const s16x8*)(V + row * 128 + ((64 * sh + 16 * g) ^ x));
                oacc[s2] = __builtin_amdgcn_mfma_f32_16x16x32_bf16(pf, vf, oacc[s2], 0, 0, 0);
            }
        }

        if (st + 1 < NT) {
            char* Kn = cur ? Kb0 : Kb1;
            char* Vn = cur ? Vb0 : Vb1;
            #pragma unroll
            for (int c = 0; c < 2; ++c) {
                int row = c * 32 + srow;
                int sw  = scol ^ ((row & 7) << 4);
                *(uint4*)(Kn + row * 128 + sw) = kreg[c];
                *(uint4*)(Vn + row * 128 + sw) = vreg[c];
            }
            __syncthreads();
            cur ^= 1;
        }
    }

    float* pc = pctx + (size_t)sp * (L_ * NB * E_);
    #pragma unroll
    for (int r = 0; r < 4; ++r) {
        int q = qb0 + w * 16 + 4 * g + r;
        #pragma unroll
        for (int s2 = 0; s2 < 4; ++s2) {
            pc[((size_t)q * NB + n) * E_ + h * HD_ + s2 * 16 + c16] = oacc[s2][r];
        }
    }
    if (g == 0) {
        pml[(((size_t)sp * NB + n) * H_ + h) * L_ + qgl] = make_float2(mrun, lrun);
    }
}

// ---------------------------------------------------------------------------
// Combine the SPLIT partials -> ctx bf16 (L, NB, E)
// ---------------------------------------------------------------------------
__global__ __launch_bounds__(256)
void attn_combine_kernel(const float* __restrict__ pctx,
                         const float2* __restrict__ pml,
                         ushort_t* __restrict__ ctxb)
{
    int idx = blockIdx.x * 256 + threadIdx.x;
    int h  = (idx >> 6) & 7;
    int tq = idx >> 9;
    int q = tq >> 2, n = tq & 3;
    float O0 = pctx[idx];
    float O1 = pctx[(size_t)(L_ * NB * E_) + idx];
    float2 ml0 = pml[(((size_t)0 * NB + n) * H_ + h) * L_ + q];
    float2 ml1 = pml[(((size_t)1 * NB + n) * H_ + h) * L_ + q];
    float ms = fmaxf(ml0.x, ml1.x);
    float a0 = __expf(ml0.x - ms), a1 = __expf(ml1.x - ms);
    float num = O0 * a0 + O1 * a1;
    float den = ml0.y * a0 + ml1.y * a1;
    ctxb[idx] = f2bf(num / den);
}

// ---------------------------------------------------------------------------
// LayerNorm in-place
// ---------------------------------------------------------------------------
__global__ __launch_bounds__(256)
void ln_kernel(float* __restrict__ y, const float* __restrict__ gamma,
               const float* __restrict__ beta)
{
    __shared__ float red1[4], red2[4];
    const int row = blockIdx.x;
    const int t   = threadIdx.x;
    float* p = y + (size_t)row * E_;
    float x0 = p[t], x1 = p[t + 256];

    float s = x0 + x1;
    #pragma unroll
    for (int o = 32; o >= 1; o >>= 1) s += __shfl_down(s, o, 64);
    if ((t & 63) == 0) red1[t >> 6] = s;
    __syncthreads();
    const float mu = (red1[0] + red1[1] + red1[2] + red1[3]) * (1.0f / E_);

    const float d0 = x0 - mu, d1 = x1 - mu;
    float vs = d0 * d0 + d1 * d1;
    #pragma unroll
    for (int o = 32; o >= 1; o >>= 1) vs += __shfl_down(vs, o, 64);
    if ((t & 63) == 0) red2[t >> 6] = vs;
    __syncthreads();
    const float var  = (red2[0] + red2[1] + red2[2] + red2[3]) * (1.0f / E_);
    const float rstd = rsqrtf(var + LNEPS);

    p[t]       = d0 * rstd * gamma[t]       + beta[t];
    p[t + 256] = d1 * rstd * gamma[t + 256] + beta[t + 256];
}

extern "C" void kernel_launch(void* const* d_in, const int* in_sizes, int n_in,
                              void* d_out, int out_size, void* d_ws, size_t ws_size,
                              hipStream_t stream) {
    const float* query = (const float*)d_in[0];
    const float* value = (const float*)d_in[1];
    const float* qpos  = (const float*)d_in[2];
    const float* vpos  = (const float*)d_in[3];
    const float* ipw   = (const float*)d_in[4];
    const float* ipb   = (const float*)d_in[5];
    const float* opw   = (const float*)d_in[6];
    const float* opb   = (const float*)d_in[7];
    const float* gamma = (const float*)d_in[8];
    const float* beta  = (const float*)d_in[9];
    float* out = (float*)d_out;

    char* ws = (char*)d_ws;
    ushort_t* vbf   = (ushort_t*)(ws + (16u << 20));      // [16,24) 8192x512 bf16
    ushort_t* qbf   = (ushort_t*)(ws + (24u << 20));      // [24,28) 4096x512
    ushort_t* wbf   = (ushort_t*)(ws + (28u << 20));      // [28,29.5) ipw bf16
    ushort_t* obf   = (ushort_t*)(ws + (30u << 20));      // [30,30.5) opw bf16
    ushort_t* qrot  = (ushort_t*)(ws + (35u << 20));      // [35,39)
    ushort_t* krot  = (ushort_t*)(ws + (39u << 20));      // [39,47)
    ushort_t* vperm = (ushort_t*)(ws + (47u << 20));      // [47,55)
    ushort_t* vt    = (ushort_t*)(ws);                    // [0,8)
    ushort_t* ctxb  = (ushort_t*)(ws + (8u << 20));       // [8,12)
    float2*   pml   = (float2*)  (ws + (12u << 20));      // [12,12.5)
    float*    pctx  = (float*)   (ws + (55u << 20));      // [55,71) 16MB

    const int c0 = 262144;
    const int c1 = c0 + 524288;
    const int c2 = c1 + 98304;
    const int c3 = c2 + 32768;
    cast4_kernel<<<3584, 256, 0, stream>>>(query, value, ipw, opw,
                                           qbf, vbf, wbf, obf, c0, c1, c2, c3);

    // fused q+kv projection with rotary epilogue (1280 blocks)
    qkv_gemm_rope_kernel<<<1280, 256, 0, stream>>>(
        qbf, vbf, wbf, ipb, qpos, vpos, qrot, krot, vperm);

    vtrans_kernel<<<dim3(S_ / 64, H_, NB), 256, 0, stream>>>(vperm, vt);

    attn_mfma_kernel<<<dim3(L_ / 64, H_, NB * SPLIT), 256, 0, stream>>>(
        qrot, krot, vt, pctx, pml);
    attn_combine_kernel<<<(L_ * NB * E_) / 256, 256, 0, stream>>>(pctx, pml, ctxb);

    gemm_bf16_kernel<2, 1><<<dim3(512 / 128, 4096 / 64), 256, 0, stream>>>(
        ctxb, obf, nullptr, opb, query, out, 512);

    ln_kernel<<<L_ * NB, 256, 0, stream>>>(out, gamma, beta);
}

// Round 9
// 235.567 us; speedup vs baseline: 1.1520x; 1.1520x over previous
//
#include <hip/hip_runtime.h>
#include <math.h>

#define L_  1024
#define S_  2048
#define NB  4
#define E_  512
#define H_  8
#define HD_ 64
#define SPLIT 2

constexpr float SCALING = 0.125f;            // (E/H)^-0.5
constexpr float LOG2E   = 1.44269504f;
constexpr float LNEPS   = 1e-5f;

typedef __attribute__((ext_vector_type(8))) short s16x8;          // 8 bf16 MFMA frag
typedef __attribute__((ext_vector_type(8))) unsigned short u16x8; // 8 bf16 store
typedef __attribute__((ext_vector_type(4))) float f32x4;          // MFMA accumulator
typedef unsigned short ushort_t;

__device__ __forceinline__ unsigned short f2bf(float f) {
    unsigned u = __builtin_bit_cast(unsigned, f);
    u += 0x7fffu + ((u >> 16) & 1u);   // RNE
    return (unsigned short)(u >> 16);
}
__device__ __forceinline__ float bf2f(unsigned short h) {
    unsigned u = ((unsigned)h) << 16;
    return __builtin_bit_cast(float, u);
}
__device__ __forceinline__ unsigned packbf(float a, float b) {
    return (unsigned)f2bf(a) | ((unsigned)f2bf(b) << 16);
}

// ---------------------------------------------------------------------------
// Kernel 0: cast 4 fp32 arrays -> bf16 (query, value, ipw, opw)
// ---------------------------------------------------------------------------
__global__ __launch_bounds__(256)
void cast4_kernel(const float* __restrict__ s0, const float* __restrict__ s1,
                  const float* __restrict__ s2, const float* __restrict__ s3,
                  ushort_t* __restrict__ d0, ushort_t* __restrict__ d1,
                  ushort_t* __restrict__ d2, ushort_t* __restrict__ d3,
                  int c0, int c1, int c2, int c3)
{
    int i = blockIdx.x * 256 + threadIdx.x;
    const float* s; ushort_t* d; int off;
    if      (i < c0) { s = s0; d = d0; off = i; }
    else if (i < c1) { s = s1; d = d1; off = i - c0; }
    else if (i < c2) { s = s2; d = d2; off = i - c1; }
    else if (i < c3) { s = s3; d = d3; off = i - c2; }
    else return;
    const float4* sp = (const float4*)(s + (size_t)off * 8);
    float4 a = sp[0], b = sp[1];
    u16x8 o;
    o[0] = f2bf(a.x); o[1] = f2bf(a.y); o[2] = f2bf(a.z); o[3] = f2bf(a.w);
    o[4] = f2bf(b.x); o[5] = f2bf(b.y); o[6] = f2bf(b.z); o[7] = f2bf(b.w);
    *(u16x8*)(d + (size_t)off * 8) = o;
}

// ---------------------------------------------------------------------------
// Combined q+kv projection GEMM (one dispatch, 640 blocks).
// 128x128 tiles, BK=32, 256 thr = 4 waves (2x2), bf16 C out.
// bid<128: q (M=4096, nfeat=512); else kv (M=8192, nfeat=1024).
// ---------------------------------------------------------------------------
__global__ __launch_bounds__(256)
void qkv_gemm_kernel(const ushort_t* __restrict__ qbf,
                     const ushort_t* __restrict__ vbf,
                     const ushort_t* __restrict__ wbf,
                     ushort_t* __restrict__ qC,
                     ushort_t* __restrict__ kvC)
{
    __shared__ ushort_t As[128 * 32];
    __shared__ ushort_t Bs[128 * 32];
    const int t = threadIdx.x;
    const int w = t >> 6, l = t & 63;
    const int wr = w >> 1, wc = w & 1;
    const int g = l >> 4, c16 = l & 15;

    const int bid = blockIdx.x;
    const ushort_t *A, *W;
    ushort_t* C;
    int nfeat, m0, n0;
    if (bid < 128) {
        A = qbf; W = wbf; C = qC; nfeat = 512;
        n0 = (bid & 3) * 128; m0 = (bid >> 2) * 128;
    } else {
        int b = bid - 128;
        A = vbf; W = wbf + 512 * 512; C = kvC; nfeat = 1024;
        n0 = (b & 7) * 128; m0 = (b >> 3) * 128;
    }

    f32x4 acc[4][4];
    #pragma unroll
    for (int m = 0; m < 4; ++m)
        #pragma unroll
        for (int n = 0; n < 4; ++n) acc[m][n] = (f32x4){0.f, 0.f, 0.f, 0.f};

    for (int k0 = 0; k0 < 512; k0 += 32) {
        #pragma unroll
        for (int ch = t; ch < 512; ch += 256) {
            int r = ch >> 2, c = ch & 3;
            s16x8 v = *(const s16x8*)(A + (size_t)(m0 + r) * 512 + k0 + c * 8);
            int cp = c ^ ((r >> 1) & 3);
            *(s16x8*)((char*)As + r * 64 + cp * 16) = v;
        }
        #pragma unroll
        for (int ch = t; ch < 512; ch += 256) {
            int r = ch >> 2, c = ch & 3;
            s16x8 v = *(const s16x8*)(W + (size_t)(n0 + r) * 512 + k0 + c * 8);
            int cp = c ^ ((r >> 1) & 3);
            *(s16x8*)((char*)Bs + r * 64 + cp * 16) = v;
        }
        __syncthreads();
        s16x8 fa[4], fb[4];
        #pragma unroll
        for (int m = 0; m < 4; ++m) {
            int r = wr * 64 + m * 16 + c16;
            fa[m] = *(const s16x8*)((char*)As + r * 64 + ((g ^ ((r >> 1) & 3)) * 16));
        }
        #pragma unroll
        for (int n = 0; n < 4; ++n) {
            int r = wc * 64 + n * 16 + c16;
            fb[n] = *(const s16x8*)((char*)Bs + r * 64 + ((g ^ ((r >> 1) & 3)) * 16));
        }
        #pragma unroll
        for (int m = 0; m < 4; ++m)
            #pragma unroll
            for (int n = 0; n < 4; ++n)
                acc[m][n] = __builtin_amdgcn_mfma_f32_16x16x32_bf16(fa[m], fb[n], acc[m][n], 0, 0, 0);
        __syncthreads();
    }

    #pragma unroll
    for (int m = 0; m < 4; ++m) {
        #pragma unroll
        for (int n = 0; n < 4; ++n) {
            int col = n0 + wc * 64 + n * 16 + c16;
            #pragma unroll
            for (int r = 0; r < 4; ++r) {
                int row = m0 + wr * 64 + m * 16 + g * 4 + r;
                C[(size_t)row * nfeat + col] = f2bf(acc[m][n][r]);
            }
        }
    }
}

// ---------------------------------------------------------------------------
// bf16 MFMA GEMM template (used for out projection, MR=1: 32x128 tiles)
// ---------------------------------------------------------------------------
template<int MR, int EPI>
__global__ __launch_bounds__(256)
void gemm_bf16_kernel(const ushort_t* __restrict__ A,
                      const ushort_t* __restrict__ Bw,
                      ushort_t* __restrict__ Cb,
                      const float* __restrict__ bias,
                      const float* __restrict__ resid,
                      float* __restrict__ Y,
                      int nfeat)
{
    constexpr int BM = MR * 32;
    __shared__ ushort_t As[BM * 32];
    __shared__ ushort_t Bs[128 * 32];
    const int t = threadIdx.x;
    const int w = t >> 6, l = t & 63;
    const int wr = w >> 1, wc = w & 1;
    const int g = l >> 4, c16 = l & 15;
    const int m0 = blockIdx.y * BM;
    const int n0 = blockIdx.x * 128;

    f32x4 acc[MR][4];
    #pragma unroll
    for (int m = 0; m < MR; ++m)
        #pragma unroll
        for (int n = 0; n < 4; ++n) acc[m][n] = (f32x4){0.f, 0.f, 0.f, 0.f};

    for (int k0 = 0; k0 < 512; k0 += 32) {
        #pragma unroll
        for (int ch = t; ch < BM * 4; ch += 256) {
            int r = ch >> 2, c = ch & 3;
            s16x8 v = *(const s16x8*)(A + (size_t)(m0 + r) * 512 + k0 + c * 8);
            int cp = c ^ ((r >> 1) & 3);
            *(s16x8*)((char*)As + r * 64 + cp * 16) = v;
        }
        #pragma unroll
        for (int ch = t; ch < 512; ch += 256) {
            int r = ch >> 2, c = ch & 3;
            s16x8 v = *(const s16x8*)(Bw + (size_t)(n0 + r) * 512 + k0 + c * 8);
            int cp = c ^ ((r >> 1) & 3);
            *(s16x8*)((char*)Bs + r * 64 + cp * 16) = v;
        }
        __syncthreads();
        s16x8 fa[MR], fb[4];
        #pragma unroll
        for (int m = 0; m < MR; ++m) {
            int r = wr * (MR * 16) + m * 16 + c16;
            fa[m] = *(const s16x8*)((char*)As + r * 64 + ((g ^ ((r >> 1) & 3)) * 16));
        }
        #pragma unroll
        for (int n = 0; n < 4; ++n) {
            int r = wc * 64 + n * 16 + c16;
            fb[n] = *(const s16x8*)((char*)Bs + r * 64 + ((g ^ ((r >> 1) & 3)) * 16));
        }
        #pragma unroll
        for (int m = 0; m < MR; ++m)
            #pragma unroll
            for (int n = 0; n < 4; ++n)
                acc[m][n] = __builtin_amdgcn_mfma_f32_16x16x32_bf16(fa[m], fb[n], acc[m][n], 0, 0, 0);
        __syncthreads();
    }

    #pragma unroll
    for (int m = 0; m < MR; ++m) {
        #pragma unroll
        for (int n = 0; n < 4; ++n) {
            int col = n0 + wc * 64 + n * 16 + c16;
            #pragma unroll
            for (int r = 0; r < 4; ++r) {
                int row = m0 + wr * (MR * 16) + m * 16 + g * 4 + r;
                if (EPI == 0) {
                    Cb[(size_t)row * nfeat + col] = f2bf(acc[m][n][r]);
                } else {
                    float v = acc[m][n][r] + bias[col] + resid[(size_t)row * 512 + col];
                    Y[(size_t)row * 512 + col] = v;
                }
            }
        }
    }
}

// ---------------------------------------------------------------------------
// epi_q: qrot = rotary((C + bias) * SCALING*LOG2E), bf16 -> (NB,H,L,64)
// (log2e folded in so attention can use exp2)
// ---------------------------------------------------------------------------
__global__ __launch_bounds__(256)
void epi_q_kernel(const ushort_t* __restrict__ Cq,
                  const float* __restrict__ bias,
                  const float* __restrict__ qpos,
                  ushort_t* __restrict__ qrot)
{
    const float sc = SCALING * LOG2E;
    int tid = blockIdx.x * 256 + threadIdx.x;
    int token = tid >> 6;
    int fo = (tid & 63) * 8;
    int lq = token >> 2, n = token & 3;
    u16x8 cv = *(const u16x8*)(Cq + (size_t)token * 512 + fo);
    const float4* bp = (const float4*)(bias + fo);
    float4 b0 = bp[0], b1 = bp[1];
    float x[8];
    x[0] = (bf2f(cv[0]) + b0.x) * sc; x[1] = (bf2f(cv[1]) + b0.y) * sc;
    x[2] = (bf2f(cv[2]) + b0.z) * sc; x[3] = (bf2f(cv[3]) + b0.w) * sc;
    x[4] = (bf2f(cv[4]) + b1.x) * sc; x[5] = (bf2f(cv[5]) + b1.y) * sc;
    x[6] = (bf2f(cv[6]) + b1.z) * sc; x[7] = (bf2f(cv[7]) + b1.w) * sc;
    const float* pp = qpos + ((size_t)(n * L_ + lq) * 512 + fo) * 2;
    u16x8 o;
    #pragma unroll
    for (int jp = 0; jp < 4; ++jp) {
        float4 p = *(const float4*)(pp + jp * 4);
        float v0 = x[2 * jp], v1 = x[2 * jp + 1];
        o[2 * jp]     = f2bf(v0 * p.x - v1 * p.y);
        o[2 * jp + 1] = f2bf(v1 * p.z + v0 * p.w);
    }
    int h = fo >> 6, hd = fo & 63;
    *(u16x8*)(qrot + ((size_t)((n * H_ + h) * L_ + lq)) * HD_ + hd) = o;
}

__global__ __launch_bounds__(256)
void epi_kv_kernel(const ushort_t* __restrict__ Ckv,
                   const float* __restrict__ bias,
                   const float* __restrict__ vpos,
                   ushort_t* __restrict__ krot,
                   ushort_t* __restrict__ vperm)
{
    int tid = blockIdx.x * 256 + threadIdx.x;
    int token = tid >> 7;
    int fo = (tid & 127) * 8;
    int s = token >> 2, n = token & 3;
    u16x8 cv = *(const u16x8*)(Ckv + (size_t)token * 1024 + fo);
    const float4* bp = (const float4*)(bias + fo);
    float4 b0 = bp[0], b1 = bp[1];
    float x[8];
    x[0] = bf2f(cv[0]) + b0.x; x[1] = bf2f(cv[1]) + b0.y;
    x[2] = bf2f(cv[2]) + b0.z; x[3] = bf2f(cv[3]) + b0.w;
    x[4] = bf2f(cv[4]) + b1.x; x[5] = bf2f(cv[5]) + b1.y;
    x[6] = bf2f(cv[6]) + b1.z; x[7] = bf2f(cv[7]) + b1.w;
    u16x8 o;
    if (fo < 512) {
        const float* pp = vpos + ((size_t)(n * S_ + s) * 512 + fo) * 2;
        #pragma unroll
        for (int jp = 0; jp < 4; ++jp) {
            float4 p = *(const float4*)(pp + jp * 4);
            float v0 = x[2 * jp], v1 = x[2 * jp + 1];
            o[2 * jp]     = f2bf(v0 * p.x - v1 * p.y);
            o[2 * jp + 1] = f2bf(v1 * p.z + v0 * p.w);
        }
        int h = fo >> 6, hd = fo & 63;
        *(u16x8*)(krot + ((size_t)((n * H_ + h) * S_ + s)) * HD_ + hd) = o;
    } else {
        #pragma unroll
        for (int j = 0; j < 8; ++j) o[j] = f2bf(x[j]);
        int f = fo - 512;
        int h = f >> 6, hd = f & 63;
        *(u16x8*)(vperm + ((size_t)((n * H_ + h) * S_ + s)) * HD_ + hd) = o;
    }
}

// ---------------------------------------------------------------------------
// V transpose (NB,H,S,64) -> (NB,H,64,S)
// ---------------------------------------------------------------------------
__global__ __launch_bounds__(256)
void vtrans_kernel(const ushort_t* __restrict__ vin,
                   ushort_t* __restrict__ vout)
{
    __shared__ ushort_t T[64][68];
    const int t  = threadIdx.x;
    const int s0 = blockIdx.x * 64;
    const int h  = blockIdx.y, n = blockIdx.z;
    const ushort_t* src = vin + (size_t)((n * H_ + h) * S_ + s0) * HD_;
    #pragma unroll
    for (int p = 0; p < 4; ++p) {
        int e = p * 1024 + t * 4;
        int row = e >> 6, col = e & 63;
        *(ushort4*)&T[row][col] = *(const ushort4*)(src + row * HD_ + col);
    }
    __syncthreads();
    ushort_t* dst = vout + (size_t)(n * H_ + h) * HD_ * S_ + s0;
    #pragma unroll
    for (int p = 0; p < 4; ++p) {
        int d  = p * 16 + (t >> 4);
        int sc = (t & 15) * 4;
        ushort4 o;
        o.x = T[sc + 0][d]; o.y = T[sc + 1][d]; o.z = T[sc + 2][d]; o.w = T[sc + 3][d];
        *(ushort4*)(dst + (size_t)d * S_ + sc) = o;
    }
}

// ---------------------------------------------------------------------------
// MFMA flash attention: swapped QK^T, S-split partials, exp2 + defer-max.
// Scores arrive pre-scaled by log2e, so softmax uses exp2 throughout;
// running max m is in log2 domain (combine kernel matches).
// ---------------------------------------------------------------------------
__global__ __launch_bounds__(256)
void attn_mfma_kernel(const ushort_t* __restrict__ qg,
                      const ushort_t* __restrict__ kg,
                      const ushort_t* __restrict__ vtg,
                      float* __restrict__ pctx,
                      float2* __restrict__ pml)
{
    __shared__ __align__(16) char smem[40960];
    char* Kb0 = smem;
    char* Kb1 = smem + 8192;
    char* Vb0 = smem + 16384;
    char* Vb1 = smem + 24576;
    const int t = threadIdx.x;
    const int w = t >> 6, l = t & 63;
    char* Ps = smem + 32768 + w * 2048;
    const int g = l >> 4, c16 = l & 15;
    const int h = blockIdx.y;
    const int n = blockIdx.z / SPLIT, sp = blockIdx.z % SPLIT;
    const int qb0 = blockIdx.x * 64;
    constexpr int NT = (S_ / SPLIT) / 64;

    const char* kbase  = (const char*)(kg  + (size_t)(n * H_ + h) * S_ * HD_)
                       + (size_t)sp * (S_ / SPLIT) * 128;
    const char* vtbase = (const char*)(vtg + (size_t)(n * H_ + h) * HD_ * S_)
                       + (size_t)sp * (S_ / SPLIT) * 2;

    const int qgl = qb0 + w * 16 + c16;
    const char* qrow = (const char*)(qg + (size_t)((n * H_ + h) * L_ + qgl) * HD_);
    s16x8 qf0 = *(const s16x8*)(qrow + 16 * g);
    s16x8 qf1 = *(const s16x8*)(qrow + 64 + 16 * g);

    const int srow = t >> 3;
    const int scol = (t & 7) * 16;

    float mrun = -1e30f, lrun = 0.f;
    f32x4 oacc[4];
    #pragma unroll
    for (int s2 = 0; s2 < 4; ++s2) oacc[s2] = (f32x4){0.f, 0.f, 0.f, 0.f};

    uint4 kreg[2], vreg[2];
    #pragma unroll
    for (int c = 0; c < 2; ++c) {
        int row = c * 32 + srow;
        kreg[c] = *(const uint4*)(kbase  + (size_t)row * 128 + scol);
        vreg[c] = *(const uint4*)(vtbase + (size_t)row * (S_ * 2) + scol);
    }
    #pragma unroll
    for (int c = 0; c < 2; ++c) {
        int row = c * 32 + srow;
        int sw  = scol ^ ((row & 7) << 4);
        *(uint4*)(Kb0 + row * 128 + sw) = kreg[c];
        *(uint4*)(Vb0 + row * 128 + sw) = vreg[c];
    }
    __syncthreads();

    int cur = 0;
    for (int st = 0; st < NT; ++st) {
        if (st + 1 < NT) {
            const char* kP = kbase  + (size_t)(st + 1) * 64 * 128;
            const char* vP = vtbase + (size_t)(st + 1) * 128;
            #pragma unroll
            for (int c = 0; c < 2; ++c) {
                int row = c * 32 + srow;
                kreg[c] = *(const uint4*)(kP + (size_t)row * 128 + scol);
                vreg[c] = *(const uint4*)(vP + (size_t)row * (S_ * 2) + scol);
            }
        }
        char* K = cur ? Kb1 : Kb0;
        char* V = cur ? Vb1 : Vb0;

        f32x4 sacc[4];
        #pragma unroll
        for (int sub = 0; sub < 4; ++sub) {
            int row = sub * 16 + c16;
            int x = (row & 7) << 4;
            s16x8 kf0 = *(const s16x8*)(K + row * 128 + ((16 * g) ^ x));
            s16x8 kf1 = *(const s16x8*)(K + row * 128 + ((64 + 16 * g) ^ x));
            f32x4 z = (f32x4){0.f, 0.f, 0.f, 0.f};
            z = __builtin_amdgcn_mfma_f32_16x16x32_bf16(kf0, qf0, z, 0, 0, 0);
            z = __builtin_amdgcn_mfma_f32_16x16x32_bf16(kf1, qf1, z, 0, 0, 0);
            sacc[sub] = z;   // sacc[sub][r] = S[q=c16][s = 16*sub + 4*g + r] (log2-scaled)
        }

        // tile max for this q row (reduce over g groups)
        float mloc = sacc[0][0];
        #pragma unroll
        for (int sub = 0; sub < 4; ++sub)
            #pragma unroll
            for (int r = 0; r < 4; ++r) mloc = fmaxf(mloc, sacc[sub][r]);
        mloc = fmaxf(mloc, __shfl_xor(mloc, 16, 64));
        mloc = fmaxf(mloc, __shfl_xor(mloc, 32, 64));

        // defer-max: only rescale when the max actually grew materially
        if (!__all(mloc - mrun <= 8.0f)) {
            float mnew = fmaxf(mrun, mloc);
            float scl = exp2f(mrun - mnew);
            float sclr[4];
            #pragma unroll
            for (int r = 0; r < 4; ++r) sclr[r] = __shfl(scl, 4 * g + r, 16);
            #pragma unroll
            for (int s2 = 0; s2 < 4; ++s2)
                #pragma unroll
                for (int r = 0; r < 4; ++r) oacc[s2][r] *= sclr[r];
            lrun *= scl;
            mrun = mnew;
        }

        float p[4][4];
        float ps = 0.f;
        #pragma unroll
        for (int sub = 0; sub < 4; ++sub)
            #pragma unroll
            for (int r = 0; r < 4; ++r) {
                float e = exp2f(sacc[sub][r] - mrun);   // bounded by 2^8
                p[sub][r] = e;
                ps += e;
            }
        ps += __shfl_xor(ps, 16, 64);
        ps += __shfl_xor(ps, 32, 64);
        lrun += ps;

        #pragma unroll
        for (int sub = 0; sub < 4; ++sub) {
            uint2 pk;
            pk.x = packbf(p[sub][0], p[sub][1]);
            pk.y = packbf(p[sub][2], p[sub][3]);
            int by = (32 * sub + 8 * g) ^ ((c16 & 7) << 4);
            *(uint2*)(Ps + c16 * 128 + by) = pk;
        }

        #pragma unroll
        for (int sh = 0; sh < 2; ++sh) {
            s16x8 pf = *(const s16x8*)(Ps + c16 * 128 + ((64 * sh + 16 * g) ^ ((c16 & 7) << 4)));
            #pragma unroll
            for (int s2 = 0; s2 < 4; ++s2) {
                int row = s2 * 16 + c16;
                int x = (row & 7) << 4;
                s16x8 vf = *(const s16x8*)(V + row * 128 + ((64 * sh + 16 * g) ^ x));
                oacc[s2] = __builtin_amdgcn_mfma_f32_16x16x32_bf16(pf, vf, oacc[s2], 0, 0, 0);
            }
        }

        if (st + 1 < NT) {
            char* Kn = cur ? Kb0 : Kb1;
            char* Vn = cur ? Vb0 : Vb1;
            #pragma unroll
            for (int c = 0; c < 2; ++c) {
                int row = c * 32 + srow;
                int sw  = scol ^ ((row & 7) << 4);
                *(uint4*)(Kn + row * 128 + sw) = kreg[c];
                *(uint4*)(Vn + row * 128 + sw) = vreg[c];
            }
            __syncthreads();
            cur ^= 1;
        }
    }

    float* pc = pctx + (size_t)sp * (L_ * NB * E_);
    #pragma unroll
    for (int r = 0; r < 4; ++r) {
        int q = qb0 + w * 16 + 4 * g + r;
        #pragma unroll
        for (int s2 = 0; s2 < 4; ++s2) {
            pc[((size_t)q * NB + n) * E_ + h * HD_ + s2 * 16 + c16] = oacc[s2][r];
        }
    }
    if (g == 0) {
        pml[(((size_t)sp * NB + n) * H_ + h) * L_ + qgl] = make_float2(mrun, lrun);
    }
}

// ---------------------------------------------------------------------------
// Combine SPLIT partials -> ctx bf16 (m is log2-domain -> exp2)
// ---------------------------------------------------------------------------
__global__ __launch_bounds__(256)
void attn_combine_kernel(const float* __restrict__ pctx,
                         const float2* __restrict__ pml,
                         ushort_t* __restrict__ ctxb)
{
    int idx = blockIdx.x * 256 + threadIdx.x;
    int h  = (idx >> 6) & 7;
    int tq = idx >> 9;
    int q = tq >> 2, n = tq & 3;
    float O0 = pctx[idx];
    float O1 = pctx[(size_t)(L_ * NB * E_) + idx];
    float2 ml0 = pml[(((size_t)0 * NB + n) * H_ + h) * L_ + q];
    float2 ml1 = pml[(((size_t)1 * NB + n) * H_ + h) * L_ + q];
    float ms = fmaxf(ml0.x, ml1.x);
    float a0 = exp2f(ml0.x - ms), a1 = exp2f(ml1.x - ms);
    float num = O0 * a0 + O1 * a1;
    float den = ml0.y * a0 + ml1.y * a1;
    ctxb[idx] = f2bf(num / den);
}

// ---------------------------------------------------------------------------
// LayerNorm in-place
// ---------------------------------------------------------------------------
__global__ __launch_bounds__(256)
void ln_kernel(float* __restrict__ y, const float* __restrict__ gamma,
               const float* __restrict__ beta)
{
    __shared__ float red1[4], red2[4];
    const int row = blockIdx.x;
    const int t   = threadIdx.x;
    float* p = y + (size_t)row * E_;
    float x0 = p[t], x1 = p[t + 256];

    float s = x0 + x1;
    #pragma unroll
    for (int o = 32; o >= 1; o >>= 1) s += __shfl_down(s, o, 64);
    if ((t & 63) == 0) red1[t >> 6] = s;
    __syncthreads();
    const float mu = (red1[0] + red1[1] + red1[2] + red1[3]) * (1.0f / E_);

    const float d0 = x0 - mu, d1 = x1 - mu;
    float vs = d0 * d0 + d1 * d1;
    #pragma unroll
    for (int o = 32; o >= 1; o >>= 1) vs += __shfl_down(vs, o, 64);
    if ((t & 63) == 0) red2[t >> 6] = vs;
    __syncthreads();
    const float var  = (red2[0] + red2[1] + red2[2] + red2[3]) * (1.0f / E_);
    const float rstd = rsqrtf(var + LNEPS);

    p[t]       = d0 * rstd * gamma[t]       + beta[t];
    p[t + 256] = d1 * rstd * gamma[t + 256] + beta[t + 256];
}

extern "C" void kernel_launch(void* const* d_in, const int* in_sizes, int n_in,
                              void* d_out, int out_size, void* d_ws, size_t ws_size,
                              hipStream_t stream) {
    const float* query = (const float*)d_in[0];
    const float* value = (const float*)d_in[1];
    const float* qpos  = (const float*)d_in[2];
    const float* vpos  = (const float*)d_in[3];
    const float* ipw   = (const float*)d_in[4];
    const float* ipb   = (const float*)d_in[5];
    const float* opw   = (const float*)d_in[6];
    const float* opb   = (const float*)d_in[7];
    const float* gamma = (const float*)d_in[8];
    const float* beta  = (const float*)d_in[9];
    float* out = (float*)d_out;

    char* ws = (char*)d_ws;
    ushort_t* kvC   = (ushort_t*)(ws);                    // [0,16) dead after epi_kv
    ushort_t* vbf   = (ushort_t*)(ws + (16u << 20));      // [16,24) dead after qkv GEMM
    ushort_t* qbf   = (ushort_t*)(ws + (24u << 20));      // [24,28) dead after qkv GEMM
    ushort_t* wbf   = (ushort_t*)(ws + (28u << 20));      // [28,29.5) dead after qkv GEMM
    ushort_t* obf   = (ushort_t*)(ws + (30u << 20));      // [30,30.5) live to out GEMM
    ushort_t* qC    = (ushort_t*)(ws + (31u << 20));      // [31,35)
    ushort_t* qrot  = (ushort_t*)(ws + (35u << 20));      // [35,39)
    ushort_t* krot  = (ushort_t*)(ws + (39u << 20));      // [39,47)
    ushort_t* vperm = (ushort_t*)(ws + (47u << 20));      // [47,55)
    ushort_t* vt    = (ushort_t*)(ws);                    // [0,8)  reuse kvC
    ushort_t* ctxb  = (ushort_t*)(ws + (8u << 20));       // [8,12) reuse kvC
    float2*   pml   = (float2*)  (ws + (12u << 20));      // [12,12.5)
    float*    pctx  = (float*)   (ws + (13u << 20));      // [13,29) over dead vbf/qbf/wbf

    const int c0 = 262144;
    const int c1 = c0 + 524288;
    const int c2 = c1 + 98304;
    const int c3 = c2 + 32768;
    cast4_kernel<<<3584, 256, 0, stream>>>(query, value, ipw, opw,
                                           qbf, vbf, wbf, obf, c0, c1, c2, c3);

    // combined q+kv projection GEMM (640 blocks, one dispatch)
    qkv_gemm_kernel<<<640, 256, 0, stream>>>(qbf, vbf, wbf, qC, kvC);

    epi_q_kernel<<<1024, 256, 0, stream>>>(qC, ipb, qpos, qrot);
    epi_kv_kernel<<<4096, 256, 0, stream>>>(kvC, ipb + E_, vpos, krot, vperm);

    vtrans_kernel<<<dim3(S_ / 64, H_, NB), 256, 0, stream>>>(vperm, vt);

    attn_mfma_kernel<<<dim3(L_ / 64, H_, NB * SPLIT), 256, 0, stream>>>(
        qrot, krot, vt, pctx, pml);
    attn_combine_kernel<<<(L_ * NB * E_) / 256, 256, 0, stream>>>(pctx, pml, ctxb);

    // out GEMM fused: Y = ctx @ Wout^T + bout + query  (512 blocks)
    gemm_bf16_kernel<1, 1><<<dim3(512 / 128, 4096 / 32), 256, 0, stream>>>(
        ctxb, obf, nullptr, opb, query, out, 512);

    ln_kernel<<<L_ * NB, 256, 0, stream>>>(out, gamma, beta);
}

// Round 10
// 216.464 us; speedup vs baseline: 1.2536x; 1.0883x over previous
//
#include <hip/hip_runtime.h>
#include <math.h>

#define L_  1024
#define S_  2048
#define NB  4
#define E_  512
#define H_  8
#define HD_ 64
#define SPLIT 2

constexpr float SCALING = 0.125f;            // (E/H)^-0.5
constexpr float LOG2E   = 1.44269504f;
constexpr float LNEPS   = 1e-5f;

typedef __attribute__((ext_vector_type(8))) short s16x8;          // 8 bf16 MFMA frag
typedef __attribute__((ext_vector_type(8))) unsigned short u16x8; // 8 bf16 store
typedef __attribute__((ext_vector_type(4))) float f32x4;          // MFMA accumulator
typedef unsigned short ushort_t;

__device__ __forceinline__ unsigned short f2bf(float f) {
    unsigned u = __builtin_bit_cast(unsigned, f);
    u += 0x7fffu + ((u >> 16) & 1u);   // RNE
    return (unsigned short)(u >> 16);
}
__device__ __forceinline__ float bf2f(unsigned short h) {
    unsigned u = ((unsigned)h) << 16;
    return __builtin_bit_cast(float, u);
}
__device__ __forceinline__ unsigned cvtpk(float lo, float hi) {
    unsigned r;
    asm("v_cvt_pk_bf16_f32 %0, %1, %2" : "=v"(r) : "v"(lo), "v"(hi));
    return r;
}
__device__ __forceinline__ void gload16(const void* g, void* l) {
    __builtin_amdgcn_global_load_lds(
        (const __attribute__((address_space(1))) void*)g,
        (__attribute__((address_space(3))) void*)l, 16, 0, 0);
}

// ---------------------------------------------------------------------------
// Kernel 0: cast 4 fp32 arrays -> bf16 (query, value, ipw, opw)
// ---------------------------------------------------------------------------
__global__ __launch_bounds__(256)
void cast4_kernel(const float* __restrict__ s0, const float* __restrict__ s1,
                  const float* __restrict__ s2, const float* __restrict__ s3,
                  ushort_t* __restrict__ d0, ushort_t* __restrict__ d1,
                  ushort_t* __restrict__ d2, ushort_t* __restrict__ d3,
                  int c0, int c1, int c2, int c3)
{
    int i = blockIdx.x * 256 + threadIdx.x;
    const float* s; ushort_t* d; int off;
    if      (i < c0) { s = s0; d = d0; off = i; }
    else if (i < c1) { s = s1; d = d1; off = i - c0; }
    else if (i < c2) { s = s2; d = d2; off = i - c1; }
    else if (i < c3) { s = s3; d = d3; off = i - c2; }
    else return;
    const float4* sp = (const float4*)(s + (size_t)off * 8);
    float4 a = sp[0], b = sp[1];
    u16x8 o;
    o[0] = f2bf(a.x); o[1] = f2bf(a.y); o[2] = f2bf(a.z); o[3] = f2bf(a.w);
    o[4] = f2bf(b.x); o[5] = f2bf(b.y); o[6] = f2bf(b.z); o[7] = f2bf(b.w);
    *(u16x8*)(d + (size_t)off * 8) = o;
}

// ---------------------------------------------------------------------------
// Combined q+kv projection GEMM, global_load_lds staging, 640 blocks.
// 128x128 tiles, BK=32, 256 thr = 4 waves (2x2), bf16 C out.
// LDS is LINEAR; the chunk-XOR swizzle cp=c^((r>>1)&3) is applied on the
// per-lane GLOBAL source address (involution) and on the ds_read side.
// bid mapping keeps blocks sharing an A-panel on the same XCD (bid mod 8).
// ---------------------------------------------------------------------------
__global__ __launch_bounds__(256)
void qkv_gemm_kernel(const ushort_t* __restrict__ qbf,
                     const ushort_t* __restrict__ vbf,
                     const ushort_t* __restrict__ wbf,
                     ushort_t* __restrict__ qC,
                     ushort_t* __restrict__ kvC)
{
    __shared__ ushort_t As[2][4096];   // 8 KB per buffer
    __shared__ ushort_t Bs[2][4096];
    const int t = threadIdx.x;
    const int w = t >> 6, l = t & 63;
    const int wr = w >> 1, wc = w & 1;
    const int g = l >> 4, c16 = l & 15;

    const int bid = blockIdx.x;
    const ushort_t *A, *W;
    ushort_t* C;
    int nfeat, m0, n0;
    if (bid < 128) {           // q: 32 m-panels x 4 n-panels, m inner (same-XCD siblings)
        A = qbf; W = wbf; C = qC; nfeat = 512;
        m0 = (bid & 31) * 128; n0 = (bid >> 5) * 128;
    } else {                   // kv: 64 m-panels x 8 n-panels, m inner
        int b = bid - 128;
        A = vbf; W = wbf + 512 * 512; C = kvC; nfeat = 1024;
        m0 = (b & 63) * 128; n0 = (b >> 6) * 128;
    }

    // staging geometry: two 64-chunk issues per wave per matrix
    const int ch0 = w * 64 + l;
    const int r0  = ch0 >> 2, cs0 = (ch0 & 3) ^ ((r0 >> 1) & 3);
    const int ch1 = 256 + ch0;
    const int r1  = ch1 >> 2, cs1 = (ch1 & 3) ^ ((r1 >> 1) & 3);
    const ushort_t* A0 = A + (size_t)(m0 + r0) * 512 + cs0 * 8;
    const ushort_t* A1 = A + (size_t)(m0 + r1) * 512 + cs1 * 8;
    const ushort_t* W0 = W + (size_t)(n0 + r0) * 512 + cs0 * 8;
    const ushort_t* W1 = W + (size_t)(n0 + r1) * 512 + cs1 * 8;

    f32x4 acc[4][4];
    #pragma unroll
    for (int m = 0; m < 4; ++m)
        #pragma unroll
        for (int n = 0; n < 4; ++n) acc[m][n] = (f32x4){0.f, 0.f, 0.f, 0.f};

    // prologue
    gload16(A0, (char*)As[0] + w * 1024);
    gload16(A1, (char*)As[0] + 4096 + w * 1024);
    gload16(W0, (char*)Bs[0] + w * 1024);
    gload16(W1, (char*)Bs[0] + 4096 + w * 1024);
    __syncthreads();

    for (int kt = 0; kt < 16; ++kt) {
        const int cur = kt & 1;
        if (kt + 1 < 16) {
            const int nk = (kt + 1) * 32;
            const int nb = cur ^ 1;
            gload16(A0 + nk, (char*)As[nb] + w * 1024);
            gload16(A1 + nk, (char*)As[nb] + 4096 + w * 1024);
            gload16(W0 + nk, (char*)Bs[nb] + w * 1024);
            gload16(W1 + nk, (char*)Bs[nb] + 4096 + w * 1024);
        }
        s16x8 fa[4], fb[4];
        #pragma unroll
        for (int m = 0; m < 4; ++m) {
            int r = wr * 64 + m * 16 + c16;
            fa[m] = *(const s16x8*)((char*)As[cur] + r * 64 + ((g ^ ((r >> 1) & 3)) * 16));
        }
        #pragma unroll
        for (int n = 0; n < 4; ++n) {
            int r = wc * 64 + n * 16 + c16;
            fb[n] = *(const s16x8*)((char*)Bs[cur] + r * 64 + ((g ^ ((r >> 1) & 3)) * 16));
        }
        #pragma unroll
        for (int m = 0; m < 4; ++m)
            #pragma unroll
            for (int n = 0; n < 4; ++n)
                acc[m][n] = __builtin_amdgcn_mfma_f32_16x16x32_bf16(fa[m], fb[n], acc[m][n], 0, 0, 0);
        if (kt + 1 < 16) __syncthreads();
    }

    #pragma unroll
    for (int m = 0; m < 4; ++m) {
        #pragma unroll
        for (int n = 0; n < 4; ++n) {
            int col = n0 + wc * 64 + n * 16 + c16;
            #pragma unroll
            for (int r = 0; r < 4; ++r) {
                int row = m0 + wr * 64 + m * 16 + g * 4 + r;
                C[(size_t)row * nfeat + col] = f2bf(acc[m][n][r]);
            }
        }
    }
}

// ---------------------------------------------------------------------------
// epi_q: qrot = rotary((C + bias) * SCALING*LOG2E), bf16 -> (NB,H,L,64)
// ---------------------------------------------------------------------------
__global__ __launch_bounds__(256)
void epi_q_kernel(const ushort_t* __restrict__ Cq,
                  const float* __restrict__ bias,
                  const float* __restrict__ qpos,
                  ushort_t* __restrict__ qrot)
{
    const float sc = SCALING * LOG2E;
    int tid = blockIdx.x * 256 + threadIdx.x;
    int token = tid >> 6;
    int fo = (tid & 63) * 8;
    int lq = token >> 2, n = token & 3;
    u16x8 cv = *(const u16x8*)(Cq + (size_t)token * 512 + fo);
    const float4* bp = (const float4*)(bias + fo);
    float4 b0 = bp[0], b1 = bp[1];
    float x[8];
    x[0] = (bf2f(cv[0]) + b0.x) * sc; x[1] = (bf2f(cv[1]) + b0.y) * sc;
    x[2] = (bf2f(cv[2]) + b0.z) * sc; x[3] = (bf2f(cv[3]) + b0.w) * sc;
    x[4] = (bf2f(cv[4]) + b1.x) * sc; x[5] = (bf2f(cv[5]) + b1.y) * sc;
    x[6] = (bf2f(cv[6]) + b1.z) * sc; x[7] = (bf2f(cv[7]) + b1.w) * sc;
    const float* pp = qpos + ((size_t)(n * L_ + lq) * 512 + fo) * 2;
    u16x8 o;
    #pragma unroll
    for (int jp = 0; jp < 4; ++jp) {
        float4 p = *(const float4*)(pp + jp * 4);
        float v0 = x[2 * jp], v1 = x[2 * jp + 1];
        o[2 * jp]     = f2bf(v0 * p.x - v1 * p.y);
        o[2 * jp + 1] = f2bf(v1 * p.z + v0 * p.w);
    }
    int h = fo >> 6, hd = fo & 63;
    *(u16x8*)(qrot + ((size_t)((n * H_ + h) * L_ + lq)) * HD_ + hd) = o;
}

__global__ __launch_bounds__(256)
void epi_kv_kernel(const ushort_t* __restrict__ Ckv,
                   const float* __restrict__ bias,
                   const float* __restrict__ vpos,
                   ushort_t* __restrict__ krot,
                   ushort_t* __restrict__ vperm)
{
    int tid = blockIdx.x * 256 + threadIdx.x;
    int token = tid >> 7;
    int fo = (tid & 127) * 8;
    int s = token >> 2, n = token & 3;
    u16x8 cv = *(const u16x8*)(Ckv + (size_t)token * 1024 + fo);
    const float4* bp = (const float4*)(bias + fo);
    float4 b0 = bp[0], b1 = bp[1];
    float x[8];
    x[0] = bf2f(cv[0]) + b0.x; x[1] = bf2f(cv[1]) + b0.y;
    x[2] = bf2f(cv[2]) + b0.z; x[3] = bf2f(cv[3]) + b0.w;
    x[4] = bf2f(cv[4]) + b1.x; x[5] = bf2f(cv[5]) + b1.y;
    x[6] = bf2f(cv[6]) + b1.z; x[7] = bf2f(cv[7]) + b1.w;
    u16x8 o;
    if (fo < 512) {
        const float* pp = vpos + ((size_t)(n * S_ + s) * 512 + fo) * 2;
        #pragma unroll
        for (int jp = 0; jp < 4; ++jp) {
            float4 p = *(const float4*)(pp + jp * 4);
            float v0 = x[2 * jp], v1 = x[2 * jp + 1];
            o[2 * jp]     = f2bf(v0 * p.x - v1 * p.y);
            o[2 * jp + 1] = f2bf(v1 * p.z + v0 * p.w);
        }
        int h = fo >> 6, hd = fo & 63;
        *(u16x8*)(krot + ((size_t)((n * H_ + h) * S_ + s)) * HD_ + hd) = o;
    } else {
        #pragma unroll
        for (int j = 0; j < 8; ++j) o[j] = f2bf(x[j]);
        int f = fo - 512;
        int h = f >> 6, hd = f & 63;
        *(u16x8*)(vperm + ((size_t)((n * H_ + h) * S_ + s)) * HD_ + hd) = o;
    }
}

// ---------------------------------------------------------------------------
// V transpose (NB,H,S,64) -> (NB,H,64,S)
// ---------------------------------------------------------------------------
__global__ __launch_bounds__(256)
void vtrans_kernel(const ushort_t* __restrict__ vin,
                   ushort_t* __restrict__ vout)
{
    __shared__ ushort_t T[64][68];
    const int t  = threadIdx.x;
    const int s0 = blockIdx.x * 64;
    const int h  = blockIdx.y, n = blockIdx.z;
    const ushort_t* src = vin + (size_t)((n * H_ + h) * S_ + s0) * HD_;
    #pragma unroll
    for (int p = 0; p < 4; ++p) {
        int e = p * 1024 + t * 4;
        int row = e >> 6, col = e & 63;
        *(ushort4*)&T[row][col] = *(const ushort4*)(src + row * HD_ + col);
    }
    __syncthreads();
    ushort_t* dst = vout + (size_t)(n * H_ + h) * HD_ * S_ + s0;
    #pragma unroll
    for (int p = 0; p < 4; ++p) {
        int d  = p * 16 + (t >> 4);
        int sc = (t & 15) * 4;
        ushort4 o;
        o.x = T[sc + 0][d]; o.y = T[sc + 1][d]; o.z = T[sc + 2][d]; o.w = T[sc + 3][d];
        *(ushort4*)(dst + (size_t)d * S_ + sc) = o;
    }
}

// ---------------------------------------------------------------------------
// MFMA flash attention: swapped QK^T, S-split partials, exp2 + defer-max.
// K/V staged via global_load_lds (linear LDS, source-pre-swizzled);
// P packed with v_cvt_pk_bf16_f32.
// ---------------------------------------------------------------------------
__global__ __launch_bounds__(256)
void attn_mfma_kernel(const ushort_t* __restrict__ qg,
                      const ushort_t* __restrict__ kg,
                      const ushort_t* __restrict__ vtg,
                      float* __restrict__ pctx,
                      float2* __restrict__ pml)
{
    __shared__ __align__(16) char smem[40960];
    char* Kb0 = smem;
    char* Kb1 = smem + 8192;
    char* Vb0 = smem + 16384;
    char* Vb1 = smem + 24576;
    const int t = threadIdx.x;
    const int w = t >> 6, l = t & 63;
    char* Ps = smem + 32768 + w * 2048;
    const int g = l >> 4, c16 = l & 15;
    const int h = blockIdx.y;
    const int n = blockIdx.z / SPLIT, sp = blockIdx.z % SPLIT;
    const int qb0 = blockIdx.x * 64;
    constexpr int NT = (S_ / SPLIT) / 64;

    const char* kbase  = (const char*)(kg  + (size_t)(n * H_ + h) * S_ * HD_)
                       + (size_t)sp * (S_ / SPLIT) * 128;
    const char* vtbase = (const char*)(vtg + (size_t)(n * H_ + h) * HD_ * S_)
                       + (size_t)sp * (S_ / SPLIT) * 2;

    const int qgl = qb0 + w * 16 + c16;
    const char* qrow = (const char*)(qg + (size_t)((n * H_ + h) * L_ + qgl) * HD_);
    s16x8 qf0 = *(const s16x8*)(qrow + 16 * g);
    s16x8 qf1 = *(const s16x8*)(qrow + 64 + 16 * g);

    // gload staging geometry: 512 chunks per tile; wave issues 2 per matrix
    const int chA = w * 64 + l;
    const int rowA = chA >> 3, srcA = ((chA & 7) * 16) ^ ((rowA & 7) << 4);
    const int chB = 256 + chA;
    const int rowB = chB >> 3, srcB = ((chB & 7) * 16) ^ ((rowB & 7) << 4);
    const char* kA = kbase + (size_t)rowA * 128 + srcA;
    const char* kB = kbase + (size_t)rowB * 128 + srcB;
    const char* vA = vtbase + (size_t)rowA * (S_ * 2) + srcA;
    const char* vB = vtbase + (size_t)rowB * (S_ * 2) + srcB;

    float mrun = -1e30f, lrun = 0.f;
    f32x4 oacc[4];
    #pragma unroll
    for (int s2 = 0; s2 < 4; ++s2) oacc[s2] = (f32x4){0.f, 0.f, 0.f, 0.f};

    // prologue stage tile 0 into buf0
    gload16(kA, Kb0 + w * 1024);
    gload16(kB, Kb0 + 4096 + w * 1024);
    gload16(vA, Vb0 + w * 1024);
    gload16(vB, Vb0 + 4096 + w * 1024);
    __syncthreads();

    int cur = 0;
    for (int st = 0; st < NT; ++st) {
        if (st + 1 < NT) {
            const size_t ko = (size_t)(st + 1) * 64 * 128;
            const size_t vo = (size_t)(st + 1) * 128;
            char* Kn = cur ? Kb0 : Kb1;
            char* Vn = cur ? Vb0 : Vb1;
            gload16(kA + ko, Kn + w * 1024);
            gload16(kB + ko, Kn + 4096 + w * 1024);
            gload16(vA + vo, Vn + w * 1024);
            gload16(vB + vo, Vn + 4096 + w * 1024);
        }
        char* K = cur ? Kb1 : Kb0;
        char* V = cur ? Vb1 : Vb0;

        f32x4 sacc[4];
        #pragma unroll
        for (int sub = 0; sub < 4; ++sub) {
            int row = sub * 16 + c16;
            int x = (row & 7) << 4;
            s16x8 kf0 = *(const s16x8*)(K + row * 128 + ((16 * g) ^ x));
            s16x8 kf1 = *(const s16x8*)(K + row * 128 + ((64 + 16 * g) ^ x));
            f32x4 z = (f32x4){0.f, 0.f, 0.f, 0.f};
            z = __builtin_amdgcn_mfma_f32_16x16x32_bf16(kf0, qf0, z, 0, 0, 0);
            z = __builtin_amdgcn_mfma_f32_16x16x32_bf16(kf1, qf1, z, 0, 0, 0);
            sacc[sub] = z;   // sacc[sub][r] = S[q=c16][s = 16*sub + 4*g + r] (log2 scale)
        }

        float mloc = sacc[0][0];
        #pragma unroll
        for (int sub = 0; sub < 4; ++sub)
            #pragma unroll
            for (int r = 0; r < 4; ++r) mloc = fmaxf(mloc, sacc[sub][r]);
        mloc = fmaxf(mloc, __shfl_xor(mloc, 16, 64));
        mloc = fmaxf(mloc, __shfl_xor(mloc, 32, 64));

        if (!__all(mloc - mrun <= 8.0f)) {
            float mnew = fmaxf(mrun, mloc);
            float scl = exp2f(mrun - mnew);
            float sclr[4];
            #pragma unroll
            for (int r = 0; r < 4; ++r) sclr[r] = __shfl(scl, 4 * g + r, 16);
            #pragma unroll
            for (int s2 = 0; s2 < 4; ++s2)
                #pragma unroll
                for (int r = 0; r < 4; ++r) oacc[s2][r] *= sclr[r];
            lrun *= scl;
            mrun = mnew;
        }

        float p[4][4];
        float ps = 0.f;
        #pragma unroll
        for (int sub = 0; sub < 4; ++sub)
            #pragma unroll
            for (int r = 0; r < 4; ++r) {
                float e = exp2f(sacc[sub][r] - mrun);
                p[sub][r] = e;
                ps += e;
            }
        ps += __shfl_xor(ps, 16, 64);
        ps += __shfl_xor(ps, 32, 64);
        lrun += ps;

        #pragma unroll
        for (int sub = 0; sub < 4; ++sub) {
            uint2 pk;
            pk.x = cvtpk(p[sub][0], p[sub][1]);
            pk.y = cvtpk(p[sub][2], p[sub][3]);
            int by = (32 * sub + 8 * g) ^ ((c16 & 7) << 4);
            *(uint2*)(Ps + c16 * 128 + by) = pk;
        }

        #pragma unroll
        for (int sh = 0; sh < 2; ++sh) {
            s16x8 pf = *(const s16x8*)(Ps + c16 * 128 + ((64 * sh + 16 * g) ^ ((c16 & 7) << 4)));
            #pragma unroll
            for (int s2 = 0; s2 < 4; ++s2) {
                int row = s2 * 16 + c16;
                int x = (row & 7) << 4;
                s16x8 vf = *(const s16x8*)(V + row * 128 + ((64 * sh + 16 * g) ^ x));
                oacc[s2] = __builtin_amdgcn_mfma_f32_16x16x32_bf16(pf, vf, oacc[s2], 0, 0, 0);
            }
        }

        if (st + 1 < NT) {
            __syncthreads();
            cur ^= 1;
        }
    }

    float* pc = pctx + (size_t)sp * (L_ * NB * E_);
    #pragma unroll
    for (int r = 0; r < 4; ++r) {
        int q = qb0 + w * 16 + 4 * g + r;
        #pragma unroll
        for (int s2 = 0; s2 < 4; ++s2) {
            pc[((size_t)q * NB + n) * E_ + h * HD_ + s2 * 16 + c16] = oacc[s2][r];
        }
    }
    if (g == 0) {
        pml[(((size_t)sp * NB + n) * H_ + h) * L_ + qgl] = make_float2(mrun, lrun);
    }
}

// ---------------------------------------------------------------------------
// Out projection with FUSED split-combine in A-staging:
// A[row][e] = (pctx0*w0 + pctx1*w1) per (token,head) softmax-merge weights.
// 32x128 tiles, grid(128,4): the 4 n-blocks sharing an A-panel have
// bids = x, x+128, x+256, x+384 (same mod 8 -> same XCD -> L2-resident).
// B staged via global_load_lds; epilogue adds bias + residual -> f32 Y.
// ---------------------------------------------------------------------------
__global__ __launch_bounds__(256)
void out_gemm_kernel(const float* __restrict__ pctx,
                     const float2* __restrict__ pml,
                     const ushort_t* __restrict__ Bw,
                     const float* __restrict__ bias,
                     const float* __restrict__ resid,
                     float* __restrict__ Y)
{
    __shared__ ushort_t As[2][1024];   // 32x32 bf16 = 2 KB
    __shared__ ushort_t Bs[2][4096];   // 128x32 bf16 = 8 KB
    const int t = threadIdx.x;
    const int w = t >> 6, l = t & 63;
    const int wr = w >> 1, wc = w & 1;
    const int g = l >> 4, c16 = l & 15;
    const int m0 = blockIdx.x * 32;
    const int n0 = blockIdx.y * 128;

    // B gload geometry
    const int ch0 = w * 64 + l;
    const int rB0 = ch0 >> 2, cB0 = (ch0 & 3) ^ ((rB0 >> 1) & 3);
    const int ch1 = 256 + ch0;
    const int rB1 = ch1 >> 2, cB1 = (ch1 & 3) ^ ((rB1 >> 1) & 3);
    const ushort_t* W0 = Bw + (size_t)(n0 + rB0) * 512 + cB0 * 8;
    const ushort_t* W1 = Bw + (size_t)(n0 + rB1) * 512 + cB1 * 8;

    // A combine-staging (threads 0..127, one 16B chunk each)
    const int ar = t >> 2, ac = t & 3;
    const int arow = m0 + ar;
    const int aq = arow >> 2, an = arow & 3;
    const int acp = ac ^ ((ar >> 1) & 3);

    f32x4 acc[4];
    #pragma unroll
    for (int n = 0; n < 4; ++n) acc[n] = (f32x4){0.f, 0.f, 0.f, 0.f};

    auto stageA = [&](int buf, int k0) {
        if (t < 128) {
            int e0 = k0 + ac * 8;
            int hh = e0 >> 6;
            float2 ml0 = pml[(((size_t)0 * NB + an) * H_ + hh) * L_ + aq];
            float2 ml1 = pml[(((size_t)1 * NB + an) * H_ + hh) * L_ + aq];
            float ms = fmaxf(ml0.x, ml1.x);
            float a0 = exp2f(ml0.x - ms), a1 = exp2f(ml1.x - ms);
            float rd = 1.0f / (ml0.y * a0 + ml1.y * a1);
            float w0 = a0 * rd, w1 = a1 * rd;
            const float* p0 = pctx + (size_t)arow * 512 + e0;
            const float* p1 = p0 + (size_t)L_ * NB * E_;
            float4 x0 = *(const float4*)p0, x1 = *(const float4*)(p0 + 4);
            float4 y0 = *(const float4*)p1, y1 = *(const float4*)(p1 + 4);
            u16x8 o;
            o[0] = f2bf(x0.x * w0 + y0.x * w1);
            o[1] = f2bf(x0.y * w0 + y0.y * w1);
            o[2] = f2bf(x0.z * w0 + y0.z * w1);
            o[3] = f2bf(x0.w * w0 + y0.w * w1);
            o[4] = f2bf(x1.x * w0 + y1.x * w1);
            o[5] = f2bf(x1.y * w0 + y1.y * w1);
            o[6] = f2bf(x1.z * w0 + y1.z * w1);
            o[7] = f2bf(x1.w * w0 + y1.w * w1);
            *(u16x8*)((char*)As[buf] + ar * 64 + acp * 16) = o;
        }
    };

    stageA(0, 0);
    gload16(W0, (char*)Bs[0] + w * 1024);
    gload16(W1, (char*)Bs[0] + 4096 + w * 1024);
    __syncthreads();

    for (int kt = 0; kt < 16; ++kt) {
        const int cur = kt & 1;
        if (kt + 1 < 16) {
            const int nk = (kt + 1) * 32;
            const int nb = cur ^ 1;
            stageA(nb, nk);
            gload16(W0 + nk, (char*)Bs[nb] + w * 1024);
            gload16(W1 + nk, (char*)Bs[nb] + 4096 + w * 1024);
        }
        s16x8 fa, fb[4];
        {
            int r = wr * 16 + c16;
            fa = *(const s16x8*)((char*)As[cur] + r * 64 + ((g ^ ((r >> 1) & 3)) * 16));
        }
        #pragma unroll
        for (int n = 0; n < 4; ++n) {
            int r = wc * 64 + n * 16 + c16;
            fb[n] = *(const s16x8*)((char*)Bs[cur] + r * 64 + ((g ^ ((r >> 1) & 3)) * 16));
        }
        #pragma unroll
        for (int n = 0; n < 4; ++n)
            acc[n] = __builtin_amdgcn_mfma_f32_16x16x32_bf16(fa, fb[n], acc[n], 0, 0, 0);
        if (kt + 1 < 16) __syncthreads();
    }

    #pragma unroll
    for (int n = 0; n < 4; ++n) {
        int col = n0 + wc * 64 + n * 16 + c16;
        #pragma unroll
        for (int r = 0; r < 4; ++r) {
            int row = m0 + wr * 16 + g * 4 + r;
            Y[(size_t)row * 512 + col] = acc[n][r] + bias[col] + resid[(size_t)row * 512 + col];
        }
    }
}

// ---------------------------------------------------------------------------
// LayerNorm in-place
// ---------------------------------------------------------------------------
__global__ __launch_bounds__(256)
void ln_kernel(float* __restrict__ y, const float* __restrict__ gamma,
               const float* __restrict__ beta)
{
    __shared__ float red1[4], red2[4];
    const int row = blockIdx.x;
    const int t   = threadIdx.x;
    float* p = y + (size_t)row * E_;
    float x0 = p[t], x1 = p[t + 256];

    float s = x0 + x1;
    #pragma unroll
    for (int o = 32; o >= 1; o >>= 1) s += __shfl_down(s, o, 64);
    if ((t & 63) == 0) red1[t >> 6] = s;
    __syncthreads();
    const float mu = (red1[0] + red1[1] + red1[2] + red1[3]) * (1.0f / E_);

    const float d0 = x0 - mu, d1 = x1 - mu;
    float vs = d0 * d0 + d1 * d1;
    #pragma unroll
    for (int o = 32; o >= 1; o >>= 1) vs += __shfl_down(vs, o, 64);
    if ((t & 63) == 0) red2[t >> 6] = vs;
    __syncthreads();
    const float var  = (red2[0] + red2[1] + red2[2] + red2[3]) * (1.0f / E_);
    const float rstd = rsqrtf(var + LNEPS);

    p[t]       = d0 * rstd * gamma[t]       + beta[t];
    p[t + 256] = d1 * rstd * gamma[t + 256] + beta[t + 256];
}

extern "C" void kernel_launch(void* const* d_in, const int* in_sizes, int n_in,
                              void* d_out, int out_size, void* d_ws, size_t ws_size,
                              hipStream_t stream) {
    const float* query = (const float*)d_in[0];
    const float* value = (const float*)d_in[1];
    const float* qpos  = (const float*)d_in[2];
    const float* vpos  = (const float*)d_in[3];
    const float* ipw   = (const float*)d_in[4];
    const float* ipb   = (const float*)d_in[5];
    const float* opw   = (const float*)d_in[6];
    const float* opb   = (const float*)d_in[7];
    const float* gamma = (const float*)d_in[8];
    const float* beta  = (const float*)d_in[9];
    float* out = (float*)d_out;

    char* ws = (char*)d_ws;
    ushort_t* kvC   = (ushort_t*)(ws);                    // [0,16) dead after epi_kv
    ushort_t* vbf   = (ushort_t*)(ws + (16u << 20));      // [16,24) dead after qkv GEMM
    ushort_t* qbf   = (ushort_t*)(ws + (24u << 20));      // [24,28) dead after qkv GEMM
    ushort_t* wbf   = (ushort_t*)(ws + (28u << 20));      // [28,29.5) dead after qkv GEMM
    ushort_t* obf   = (ushort_t*)(ws + (30u << 20));      // [30,30.5) live to out GEMM
    ushort_t* qC    = (ushort_t*)(ws + (31u << 20));      // [31,35)
    ushort_t* qrot  = (ushort_t*)(ws + (35u << 20));      // [35,39)
    ushort_t* krot  = (ushort_t*)(ws + (39u << 20));      // [39,47)
    ushort_t* vperm = (ushort_t*)(ws + (47u << 20));      // [47,55)
    ushort_t* vt    = (ushort_t*)(ws);                    // [0,8)  reuse kvC
    float2*   pml   = (float2*)  (ws + (12u << 20));      // [12,12.5)
    float*    pctx  = (float*)   (ws + (13u << 20));      // [13,29) over dead kvC-tail/vbf/qbf

    const int c0 = 262144;
    const int c1 = c0 + 524288;
    const int c2 = c1 + 98304;
    const int c3 = c2 + 32768;
    cast4_kernel<<<3584, 256, 0, stream>>>(query, value, ipw, opw,
                                           qbf, vbf, wbf, obf, c0, c1, c2, c3);

    qkv_gemm_kernel<<<640, 256, 0, stream>>>(qbf, vbf, wbf, qC, kvC);

    epi_q_kernel<<<1024, 256, 0, stream>>>(qC, ipb, qpos, qrot);
    epi_kv_kernel<<<4096, 256, 0, stream>>>(kvC, ipb + E_, vpos, krot, vperm);

    vtrans_kernel<<<dim3(S_ / 64, H_, NB), 256, 0, stream>>>(vperm, vt);

    attn_mfma_kernel<<<dim3(L_ / 64, H_, NB * SPLIT), 256, 0, stream>>>(
        qrot, krot, vt, pctx, pml);

    // out projection + fused split-combine + bias + residual
    out_gemm_kernel<<<dim3(128, 4), 256, 0, stream>>>(
        pctx, pml, obf, opb, query, out);

    ln_kernel<<<L_ * NB, 256, 0, stream>>>(out, gamma, beta);
}